// Round 4
// baseline (286.843 us; speedup 1.0000x reference)
//
#include <hip/hip_runtime.h>
#include <hip/hip_bf16.h>

#define B_   16
#define CI_  32
#define H_   224
#define W_   224
#define CO_  32
#define OH_  222
#define OW_  222
#define HW_  (H_*W_)     // 50176
#define K_   288         // CI_*9

// Rolling-pipeline geometry v2: 512 thr / 8 waves; step = 4 oh rows x 64 ow x 32 co.
// Wave wv -> (row = wv>>1, ot-half = wv&1): acc is only [2][2] (16 VGPR).
// LDS = ring of 10 row-slabs (66 px x 32 ci bf16 = 4224 B) = 42,240 B.
// Grid 768 = exactly 3 blocks/CU -> 24 waves/CU resident, no generation tail.
#define OWTW   64
#define PXT_   66                // 64 + 2 col halo
#define NPAIR  33                // pixel pairs per row
#define RING   10
#define SLABB  (PXT_*CI_*2)      // 4224 B per row slab
#define CHROWS 20                // oh rows per block (5 steps of 4)
#define NCHUNK 12                // ceil(222/20) -> chunk 11 has 2 rows
#define NBLK   (NCHUNK*4*B_)     // 768
#define STG    264               // steady stage tasks: 4 rows x 33 pairs x 2 ci-halves
#define PRO    396               // prologue tasks: 6 rows x 33 x 2

typedef __attribute__((ext_vector_type(8))) short short8;   // 8 bf16 = 16B
typedef __attribute__((ext_vector_type(4))) float float4v;  // MFMA C/D
typedef float float4u __attribute__((ext_vector_type(4), aligned(4)));

// LDS swizzle (verified R2: conflicts 3.8M -> 0.68M): XOR bits 4-6 with 7-9.
// Same formula on write & read -> correctness independent of base alignment.
__device__ __forceinline__ unsigned swz(unsigned L) {
    return L ^ (((L >> 7) & 7u) << 4);
}

__device__ __forceinline__ int wrap10(int v) {   // v in [0, 29]
    if (v >= 20) return v - 20;
    if (v >= 10) return v - 10;
    return v;
}

// ---------------- weights: w[co][ci][kh][kw] fp32 -> wbf[co][g][ci] bf16 ----------------
__global__ void wprep(const float* __restrict__ w, unsigned short* __restrict__ wbf) {
    int idx = blockIdx.x * 256 + threadIdx.x;
    if (idx >= CO_ * K_) return;
    int co  = idx / K_;
    int rem = idx - co * K_;
    int ci  = rem / 9;
    int g   = rem - ci * 9;           // kh*3+kw
    unsigned int u = __float_as_uint(w[idx]);
    u = u + 0x7FFFu + ((u >> 16) & 1u);
    wbf[co * K_ + g * 32 + ci] = (unsigned short)(u >> 16);
}

// load one ci-half (16 planes) of one pixel pair (col-clamped). 16 float2 = 32 VGPR.
__device__ __forceinline__ void load_half(const float* __restrict__ xp, int c, int h,
                                          float2* f2) {
    const float* p = xp + (size_t)(h * 16) * HW_;
    if (c + 1 < W_) {
#pragma unroll
        for (int i = 0; i < 16; ++i)
            f2[i] = *(const float2*)&p[(size_t)i * HW_ + c];
    } else {                          // c >= 224 (owt=3 halo): both cols clamp to 223
#pragma unroll
        for (int i = 0; i < 16; ++i) {
            float v = p[(size_t)i * HW_ + (W_ - 1)];
            f2[i] = make_float2(v, v);
        }
    }
}

// convert one ci-half -> 4 short8, write swizzled chunks of the 128 B pair region.
// even px -> chunks 2h,2h+1 ; odd px -> chunks 4+2h,5+2h   (R1/R2-proven mapping)
__device__ __forceinline__ void cvt_write_half(unsigned short* Xs, int slot, int j, int h,
                                               const float2* f2) {
    union { short8 s8[4]; __hip_bfloat162 h2[16]; } u;
#pragma unroll
    for (int i = 0; i < 8; ++i) {
        u.h2[i]     = __float22bfloat162_rn(make_float2(f2[2*i].x, f2[2*i+1].x)); // even px
        u.h2[8 + i] = __float22bfloat162_rn(make_float2(f2[2*i].y, f2[2*i+1].y)); // odd px
    }
    const unsigned base = (unsigned)(slot * NPAIR + j) * 128u;
    *(short8*)((char*)Xs + swz(base + (unsigned)(2*h)     * 16u)) = u.s8[0];
    *(short8*)((char*)Xs + swz(base + (unsigned)(2*h + 1) * 16u)) = u.s8[1];
    *(short8*)((char*)Xs + swz(base + (unsigned)(4 + 2*h) * 16u)) = u.s8[2];
    *(short8*)((char*)Xs + swz(base + (unsigned)(5 + 2*h) * 16u)) = u.s8[3];
}

// ---------------- rolling double-buffered fused conv (8-wave blocks) ----------------
// Per step s (rows q = r0+4s .. q+3):
//   1) 264 threads issue next-step loads (rows q+6..q+9, one ci-half each) [issue-early]
//   2) 8 waves compute: wave -> (row = wv>>1, ot pair = wv&1), reads slabs (q..q+5)%10
//   3) convert + ds_write prefetched halves to slots (q+6..q+9)%10         [write-late]
//   4) one __syncthreads
// Ring safety: read-set and write-set are 10 consecutive rows -> distinct mod 10.
__global__ __launch_bounds__(512, 6) void conv_fused(
    const float* __restrict__ x, const unsigned short* __restrict__ wbf,
    const float* __restrict__ bias, float* __restrict__ out)
{
    __shared__ unsigned short Xs[RING * PXT_ * CI_];   // 42,240 B -> 3 blocks/CU

    const int t   = threadIdx.x;
    const int bid = blockIdx.x;
    // XCD swizzle (verified R1: WRITE 127->108 MB): 4 ow-tiles of one (b,chunk)
    // on the same XCD, temporally adjacent -> L2 merges partial output sectors.
    const int xcd   = bid & 7;
    const int owt   = (bid >> 3) & 3;
    const int gid   = (bid >> 5) * 8 + xcd;        // 0..191 = b*12 + chunk
    const int b     = gid / NCHUNK;
    const int chunk = gid - b * NCHUNK;
    const int r0    = chunk * CHROWS;
    const int ow0   = owt * OWTW;
    const int NS    = min(5, (OH_ - r0 + 3) >> 2); // chunks 0-10: 5, chunk 11: 1

    const int lane = t & 63, wv = t >> 6;
    const int i16  = lane & 15, quad = lane >> 4;

    const float* xb = x + (size_t)b * CI_ * HW_;

    float2 f2[16];                                  // prefetch regs (32 VGPR)

    // ---- prologue: stage rows r0..r0+5 -> slots 0..5 (396 half-tasks) ----
    if (t < PRO) {
        const int h  = t & 1;
        const int pj = t >> 1;                      // 0..197
        const int tr = pj / NPAIR, j = pj - tr * NPAIR;
        int gr = r0 + tr; if (gr > H_ - 1) gr = H_ - 1;   // chunk 11 clamps; unread
        load_half(xb + (size_t)gr * W_, ow0 + 2 * j, h, f2);
        cvt_write_half(Xs, tr, j, h, f2);
    }
    __syncthreads();

    const float bv0 = bias[i16];
    const float bv1 = bias[16 + i16];
    const unsigned short* wr0 = wbf + (size_t)i16 * K_;          // co = i16
    const unsigned short* wr1 = wbf + (size_t)(16 + i16) * K_;   // co = 16+i16

    const int s_h  = t & 1;                         // steady-state stage task decode
    const int s_pj = t >> 1;                        // 0..131 for t<264
    const int s_tr = s_pj / NPAIR;
    const int s_j  = s_pj - s_tr * NPAIR;
    const int s_c  = ow0 + 2 * s_j;

    const int row = wv >> 1;                        // wave's oh row within step
    const int oth = wv & 1;                         // which pair of ot's

    for (int s = 0; s < NS; ++s) {
        // ---- 1) issue next-step loads (before compute -> latency hidden) ----
        const bool pref = (t < STG) && (s + 1 < NS);
        int slotW = 0;
        if (pref) {
            const int gr0 = r0 + 4 * s + 6 + s_tr;
            slotW = wrap10(4 * s + 6 + s_tr);
            const int gr = gr0 > H_ - 1 ? H_ - 1 : gr0;
            load_half(xb + (size_t)gr * W_, s_c, s_h, f2);
        }
        __builtin_amdgcn_sched_barrier(0);   // pin load issue here (don't sink to use)

        // ---- 2) compute: wave -> oh = r0+4s+row, ot in {2*oth, 2*oth+1} ----
        const int oh = r0 + 4 * s + row;
        if (oh < OH_) {                      // wave-uniform guard; no early return
            float4v acc[2][2] = {};
            const int sl0 = 4 * s + row;
#pragma unroll
            for (int g = 0; g < 9; ++g) {
                const int kh = g / 3, kw = g - kh * 3;
                const int sl = wrap10(sl0 + kh);
                const short8 b0 = *(const short8*)&wr0[g * 32 + quad * 8];
                const short8 b1 = *(const short8*)&wr1[g * 32 + quad * 8];
                const unsigned rowbase = (unsigned)(sl * SLABB) + (unsigned)quad * 16u;
#pragma unroll
                for (int oti = 0; oti < 2; ++oti) {
                    const int ot = 2 * oth + oti;
                    const unsigned L = rowbase + (unsigned)(ot * 16 + i16 + kw) * 64u;
                    const short8 a = *(const short8*)((const char*)Xs + swz(L));
                    acc[oti][0] = __builtin_amdgcn_mfma_f32_16x16x32_bf16(a, b0, acc[oti][0], 0, 0, 0);
                    acc[oti][1] = __builtin_amdgcn_mfma_f32_16x16x32_bf16(a, b1, acc[oti][1], 0, 0, 0);
                }
            }
            // epilogue: per (oti,half) one dwordx4 -> 64B runs per co-plane
            const size_t o0 = ((size_t)(b * CO_ + i16) * OH_ + oh) * (size_t)OW_;
            const size_t o1 = ((size_t)(b * CO_ + 16 + i16) * OH_ + oh) * (size_t)OW_;
#pragma unroll
            for (int oti = 0; oti < 2; ++oti) {
                const int ot  = 2 * oth + oti;
                const int owq = ow0 + ot * 16 + quad * 4;
                float4u v0 = { acc[oti][0][0] + bv0, acc[oti][0][1] + bv0,
                               acc[oti][0][2] + bv0, acc[oti][0][3] + bv0 };
                float4u v1 = { acc[oti][1][0] + bv1, acc[oti][1][1] + bv1,
                               acc[oti][1][2] + bv1, acc[oti][1][3] + bv1 };
                if (owq + 3 < OW_) {
                    *(float4u*)&out[o0 + owq] = v0;
                    *(float4u*)&out[o1 + owq] = v1;
                } else {
#pragma unroll
                    for (int r = 0; r < 4; ++r)
                        if (owq + r < OW_) {
                            out[o0 + owq + r] = acc[oti][0][r] + bv0;
                            out[o1 + owq + r] = acc[oti][1][r] + bv1;
                        }
                }
            }
        }

        // ---- 3) write-late: convert prefetched halves into ring (disjoint slots) ----
        if (pref) cvt_write_half(Xs, slotW, s_j, s_h, f2);
        // ---- 4) one barrier per step ----
        __syncthreads();
    }
}

extern "C" void kernel_launch(void* const* d_in, const int* in_sizes, int n_in,
                              void* d_out, int out_size, void* d_ws, size_t ws_size,
                              hipStream_t stream) {
    const float* x    = (const float*)d_in[0];
    const float* w    = (const float*)d_in[1];
    const float* bias = (const float*)d_in[2];
    float* out        = (float*)d_out;
    unsigned short* wbf = (unsigned short*)d_ws;                 // 18,432 B

    wprep<<<(CO_ * K_ + 255) / 256, 256, 0, stream>>>(w, wbf);
    conv_fused<<<dim3(NBLK), 512, 0, stream>>>(x, wbf, bias, out);
}

// Round 5
// 229.251 us; speedup vs baseline: 1.2512x; 1.2512x over previous
//
#include <hip/hip_runtime.h>
#include <hip/hip_bf16.h>

#define B_   16
#define CI_  32
#define H_   224
#define W_   224
#define CO_  32
#define OH_  222
#define OW_  222
#define HW_  (H_*W_)     // 50176
#define K_   288         // CI_*9

// Producer/consumer geometry: 512 thr / 8 waves.
//   waves 0-3 = consumers: per step, wave wv computes oh row r0+4s+wv (acc[4][2]).
//   waves 4-7 = producers: per step, stage next step's 4 rows into the LDS ring.
// Register live ranges are disjoint by construction (consumers never hold f2,
// producers never hold acc) -> no spill (R4's failure mode: f2 live across
// compute overflowed the 85-VGPR cap -> 104 MB scratch traffic).
// LDS = ring of 10 row-slabs (66 px x 32 ci bf16 = 4224 B) = 42,240 B
// -> 3 blocks/CU, grid 768 = exactly 3 x 256 CUs, persistent, no tail.
#define OWTW   64
#define PXT_   66                // 64 + 2 col halo
#define NPAIR  33                // pixel pairs per row (incl. halo pair j=32)
#define RING   10
#define SLABB  (PXT_*CI_*2)      // 4224 B per row slab
#define CHROWS 20                // oh rows per block (5 steps of 4)
#define NCHUNK 12                // ceil(222/20) -> chunk 11 has 2 rows
#define NBLK   (NCHUNK*4*B_)     // 768
#define PRO    396               // prologue tasks: 6 rows x 33 pairs x 2 ci-halves

typedef __attribute__((ext_vector_type(8))) short short8;   // 8 bf16 = 16B
typedef __attribute__((ext_vector_type(4))) float float4v;  // MFMA C/D
typedef float float4u __attribute__((ext_vector_type(4), aligned(4)));

// LDS swizzle (verified R2: conflicts 3.8M -> 0.68M): XOR bits 4-6 with 7-9.
// Same formula on write & read.
__device__ __forceinline__ unsigned swz(unsigned L) {
    return L ^ (((L >> 7) & 7u) << 4);
}

__device__ __forceinline__ int wrap10(int v) {   // v in [0, 29]
    if (v >= 20) return v - 20;
    if (v >= 10) return v - 10;
    return v;
}

// ---------------- weights: w[co][ci][kh][kw] fp32 -> wbf[co][g][ci] bf16 ----------------
__global__ void wprep(const float* __restrict__ w, unsigned short* __restrict__ wbf) {
    int idx = blockIdx.x * 256 + threadIdx.x;
    if (idx >= CO_ * K_) return;
    int co  = idx / K_;
    int rem = idx - co * K_;
    int ci  = rem / 9;
    int g   = rem - ci * 9;           // kh*3+kw
    unsigned int u = __float_as_uint(w[idx]);
    u = u + 0x7FFFu + ((u >> 16) & 1u);
    wbf[co * K_ + g * 32 + ci] = (unsigned short)(u >> 16);
}

// load one ci-half (16 planes) of one pixel pair (col-clamped). 16 float2 = 32 VGPR.
__device__ __forceinline__ void load_half(const float* __restrict__ xp, int c, int h,
                                          float2* f2) {
    const float* p = xp + (size_t)(h * 16) * HW_;
    if (c + 1 < W_) {
#pragma unroll
        for (int i = 0; i < 16; ++i)
            f2[i] = *(const float2*)&p[(size_t)i * HW_ + c];
    } else {                          // c >= 224 (owt=3 halo): both cols clamp to 223
#pragma unroll
        for (int i = 0; i < 16; ++i) {
            float v = p[(size_t)i * HW_ + (W_ - 1)];
            f2[i] = make_float2(v, v);
        }
    }
}

// convert one ci-half -> 4 short8, write swizzled chunks of the 128 B pair region.
// even px -> chunks 2h,2h+1 ; odd px -> chunks 4+2h,5+2h   (R1-R4 proven mapping)
__device__ __forceinline__ void cvt_write_half(unsigned short* Xs, int slot, int j, int h,
                                               const float2* f2) {
    union { short8 s8[4]; __hip_bfloat162 h2[16]; } u;
#pragma unroll
    for (int i = 0; i < 8; ++i) {
        u.h2[i]     = __float22bfloat162_rn(make_float2(f2[2*i].x, f2[2*i+1].x)); // even px
        u.h2[8 + i] = __float22bfloat162_rn(make_float2(f2[2*i].y, f2[2*i+1].y)); // odd px
    }
    const unsigned base = (unsigned)(slot * NPAIR + j) * 128u;
    *(short8*)((char*)Xs + swz(base + (unsigned)(2*h)     * 16u)) = u.s8[0];
    *(short8*)((char*)Xs + swz(base + (unsigned)(2*h + 1) * 16u)) = u.s8[1];
    *(short8*)((char*)Xs + swz(base + (unsigned)(4 + 2*h) * 16u)) = u.s8[2];
    *(short8*)((char*)Xs + swz(base + (unsigned)(5 + 2*h) * 16u)) = u.s8[3];
}

// ---------------- producer/consumer rolling fused conv ----------------
// Per step s (rows q = r0+4s .. q+3):
//   producers (waves 4-7): load rows q+6..q+9 (one ci-half/thread), cvt,
//                          ds_write to slots (q+6..q+9)%10, wait at barrier.
//   consumers (waves 0-3): wave wv computes oh=q+wv from slabs (q..q+5)%10
//                          (ds_read + MFMA under setprio(1)), stores, barrier.
// Producer load latency is hidden by consumer compute on the same SIMDs.
// Ring safety: read-set q..q+5 and write-set q+6..q+9 are 10 consecutive rows
// -> distinct mod 10. One barrier per step.
__global__ __launch_bounds__(512, 6) void conv_fused(
    const float* __restrict__ x, const unsigned short* __restrict__ wbf,
    const float* __restrict__ bias, float* __restrict__ out)
{
    __shared__ unsigned short Xs[RING * PXT_ * CI_];   // 42,240 B -> 3 blocks/CU

    const int t   = threadIdx.x;
    const int bid = blockIdx.x;
    // XCD swizzle (verified R1: WRITE 127->108 MB): 4 ow-tiles of one (b,chunk)
    // on the same XCD, temporally adjacent -> L2 merges partial output sectors.
    const int xcd   = bid & 7;
    const int owt   = (bid >> 3) & 3;
    const int gid   = (bid >> 5) * 8 + xcd;        // 0..191 = b*12 + chunk
    const int b     = gid / NCHUNK;
    const int chunk = gid - b * NCHUNK;
    const int r0    = chunk * CHROWS;
    const int ow0   = owt * OWTW;
    const int nsr   = (OH_ - r0 + 3) >> 2;
    const int NS    = nsr < 5 ? nsr : 5;           // chunks 0-10: 5, chunk 11: 1

    const int lane = t & 63, wv = t >> 6;
    const int i16  = lane & 15, quad = lane >> 4;

    const float* xb = x + (size_t)b * CI_ * HW_;

    // ---- prologue: all waves stage rows r0..r0+5 -> slots 0..5 (396 half-tasks) ----
    {
        float2 f2[16];                  // short live range; dead before main loop
        if (t < PRO) {
            const int h  = t & 1;
            const int pj = t >> 1;                  // 0..197
            const int tr = pj / NPAIR, j = pj - tr * NPAIR;
            int gr = r0 + tr; if (gr > H_ - 1) gr = H_ - 1;   // chunk 11 clamps; unread
            load_half(xb + (size_t)gr * W_, ow0 + 2 * j, h, f2);
            cvt_write_half(Xs, tr, j, h, f2);
        }
    }
    __syncthreads();

    if (wv < 4) {
        // =================== CONSUMER: waves 0-3 ===================
        const float bv0 = bias[i16];
        const float bv1 = bias[16 + i16];
        const unsigned short* wr0 = wbf + (size_t)i16 * K_;          // co = i16
        const unsigned short* wr1 = wbf + (size_t)(16 + i16) * K_;   // co = 16+i16

        for (int s = 0; s < NS; ++s) {
            const int oh = r0 + 4 * s + wv;
            if (oh < OH_) {                  // wave-uniform guard; no early return
                float4v acc[4][2] = {};
                const int sl0 = 4 * s + wv;
                __builtin_amdgcn_s_setprio(1);   // T5: role-split exists now
#pragma unroll
                for (int g = 0; g < 9; ++g) {
                    const int kh = g / 3, kw = g - kh * 3;
                    const int sl = wrap10(sl0 + kh);
                    const short8 b0 = *(const short8*)&wr0[g * 32 + quad * 8];
                    const short8 b1 = *(const short8*)&wr1[g * 32 + quad * 8];
                    const unsigned rowbase = (unsigned)(sl * SLABB) + (unsigned)quad * 16u;
#pragma unroll
                    for (int ot = 0; ot < 4; ++ot) {
                        const unsigned L = rowbase + (unsigned)(ot * 16 + i16 + kw) * 64u;
                        const short8 a = *(const short8*)((const char*)Xs + swz(L));
                        acc[ot][0] = __builtin_amdgcn_mfma_f32_16x16x32_bf16(a, b0, acc[ot][0], 0, 0, 0);
                        acc[ot][1] = __builtin_amdgcn_mfma_f32_16x16x32_bf16(a, b1, acc[ot][1], 0, 0, 0);
                    }
                }
                __builtin_amdgcn_s_setprio(0);
                // epilogue: per (ot,half) one dwordx4 -> 64B runs per co-plane
                const size_t o0 = ((size_t)(b * CO_ + i16) * OH_ + oh) * (size_t)OW_;
                const size_t o1 = ((size_t)(b * CO_ + 16 + i16) * OH_ + oh) * (size_t)OW_;
#pragma unroll
                for (int ot = 0; ot < 4; ++ot) {
                    const int owq = ow0 + ot * 16 + quad * 4;
                    float4u v0 = { acc[ot][0][0] + bv0, acc[ot][0][1] + bv0,
                                   acc[ot][0][2] + bv0, acc[ot][0][3] + bv0 };
                    float4u v1 = { acc[ot][1][0] + bv1, acc[ot][1][1] + bv1,
                                   acc[ot][1][2] + bv1, acc[ot][1][3] + bv1 };
                    if (owq + 3 < OW_) {
                        *(float4u*)&out[o0 + owq] = v0;
                        *(float4u*)&out[o1 + owq] = v1;
                    } else {
#pragma unroll
                        for (int r = 0; r < 4; ++r)
                            if (owq + r < OW_) {
                                out[o0 + owq + r] = acc[ot][0][r] + bv0;
                                out[o1 + owq + r] = acc[ot][1][r] + bv1;
                            }
                    }
                }
            }
            __syncthreads();
        }
    } else {
        // =================== PRODUCER: waves 4-7 ===================
        // 256 threads, 4 rows x 32 pairs x 2 ci-halves = 256 main tasks;
        // 8 halo tasks (pair j=32) done serially by threads tp<8.
        const int tp   = t - 256;
        const int p_h  = tp & 1;
        const int p_u  = tp >> 1;          // 0..127
        const int p_tr = p_u >> 5;         // 0..3
        const int p_jj = p_u & 31;         // 0..31
        const int p_c  = ow0 + 2 * p_jj;

        float2 f2[16];                     // producers never hold acc -> no pressure

        for (int s = 0; s < NS; ++s) {
            if (s + 1 < NS) {
                const int base = 4 * s + 6;
                {
                    const int gr0 = r0 + base + p_tr;
                    const int gr  = gr0 > H_ - 1 ? H_ - 1 : gr0;
                    load_half(xb + (size_t)gr * W_, p_c, p_h, f2);
                    cvt_write_half(Xs, wrap10(base + p_tr), p_jj, p_h, f2);
                }
                if (tp < 8) {              // halo pair j=32 (cols ow0+64, ow0+65)
                    const int h2_ = tp & 1, tr2 = tp >> 1;
                    const int gr0 = r0 + base + tr2;
                    const int gr  = gr0 > H_ - 1 ? H_ - 1 : gr0;
                    load_half(xb + (size_t)gr * W_, ow0 + 64, h2_, f2);
                    cvt_write_half(Xs, wrap10(base + tr2), 32, h2_, f2);
                }
            }
            __syncthreads();
        }
    }
}

extern "C" void kernel_launch(void* const* d_in, const int* in_sizes, int n_in,
                              void* d_out, int out_size, void* d_ws, size_t ws_size,
                              hipStream_t stream) {
    const float* x    = (const float*)d_in[0];
    const float* w    = (const float*)d_in[1];
    const float* bias = (const float*)d_in[2];
    float* out        = (float*)d_out;
    unsigned short* wbf = (unsigned short*)d_ws;                 // 18,432 B

    wprep<<<(CO_ * K_ + 255) / 256, 256, 0, stream>>>(w, wbf);
    conv_fused<<<dim3(NBLK), 512, 0, stream>>>(x, wbf, bias, out);
}